// Round 2
// baseline (1159.583 us; speedup 1.0000x reference)
//
#include <hip/hip_runtime.h>
#include <hip/hip_bf16.h>
#include <hip/hip_fp16.h>
#include <math.h>

// Problem constants (fixed by reference)
#define N_NODES 200000
#define FDIM    256     // F
#define MDIM    128     // M
#define KMIX    8       // K mixtures
#define ATTD    128     // ATT
#define NGRAPH  1024
#define TSN     64      // nodes per block

#define EXP2(x) __builtin_amdgcn_exp2f(x)
#define LOG2E   1.44269504f

typedef _Float16 half8 __attribute__((ext_vector_type(8)));
typedef _Float16 half4 __attribute__((ext_vector_type(4)));
typedef float    floatx4 __attribute__((ext_vector_type(4)));

// ---------------------------------------------------------------------------
// Kernel 0: split g AND w1 (fp32) into fp16 hi/lo, packed in MFMA B-frag order,
// plus zero the per-graph accumulators (sumE[1024] ++ sumEH[1024][128]).
// Blocks 0..127: g.   frag idx = (k*8 + ctg)*8 + fc ; 64 lanes x half8.
// Blocks 128..135: w1. frag idx = ctg*4 + mc.
// Blocks 136..651: zero acc (516*256 = 132096 = 1024*129 exactly).
// B layout (16x16x32 f16): col = lane&15, kdim = (lane>>4)*8 + j.
// ---------------------------------------------------------------------------
__global__ __launch_bounds__(256) void pack_zero(
    const float* __restrict__ g, const float* __restrict__ w1,
    _Float16* __restrict__ gh, _Float16* __restrict__ gl,
    _Float16* __restrict__ w1h, _Float16* __restrict__ w1l,
    float* __restrict__ acc)
{
    if (blockIdx.x < 128) {
        int t    = blockIdx.x * 256 + threadIdx.x;   // 0..32767
        int lane = t & 63;
        int frag = t >> 6;         // 0..511
        int fc   = frag & 7;
        int ctg  = (frag >> 3) & 7;
        int k    = frag >> 6;
        int col  = k * 128 + ctg * 16 + (lane & 15);
        int f0   = fc * 32 + (lane >> 4) * 8;
        half8 vh, vl;
        #pragma unroll
        for (int j = 0; j < 8; ++j) {
            float v = g[(size_t)(f0 + j) * 1024 + col];
            _Float16 h = (_Float16)v;
            vh[j] = h;
            vl[j] = (_Float16)(v - (float)h);
        }
        *(half8*)(gh + (size_t)t * 8) = vh;
        *(half8*)(gl + (size_t)t * 8) = vl;
    } else if (blockIdx.x < 136) {
        int t    = (blockIdx.x - 128) * 256 + threadIdx.x;   // 0..2047
        int lane = t & 63;
        int frag = t >> 6;         // 0..31
        int mc   = frag & 3;
        int ctg  = frag >> 2;
        int att  = ctg * 16 + (lane & 15);
        int m0   = mc * 32 + (lane >> 4) * 8;
        half8 vh, vl;
        #pragma unroll
        for (int j = 0; j < 8; ++j) {
            float v = w1[att * MDIM + m0 + j];
            _Float16 h = (_Float16)v;
            vh[j] = h;
            vl[j] = (_Float16)(v - (float)h);
        }
        *(half8*)(w1h + (size_t)t * 8) = vh;
        *(half8*)(w1l + (size_t)t * 8) = vl;
    } else {
        int i = (blockIdx.x - 136) * 256 + threadIdx.x;
        if (i < NGRAPH * (MDIM + 1)) acc[i] = 0.f;
    }
}

// ---------------------------------------------------------------------------
// Kernel 1: fused x@g (fp16-split MFMA) -> gaussian -> H -> attention (MFMA)
//   -> in-block softmax-numerator pooling via f32 atomics.
//   grid: N/64 blocks x 512 threads (8 waves).
//   wave w: n-half = w>>2 (32 nodes, rt=2), col-quarter = w&3 (32 cols, ct=2).
//   R2: per-k barrier removed (no data dep; was an L1-sharing heuristic),
//       fc loop fully unrolled with 1-deep ping-pong B prefetch (hides ~200cy
//       L2 latency under 12 MFMAs), exp folded to v_exp_f32 via exp2 consts.
// ---------------------------------------------------------------------------
__global__ __launch_bounds__(512, 4) void fused_forward(
    const float* __restrict__ x,
    const _Float16* __restrict__ gh, const _Float16* __restrict__ gl,
    const float* __restrict__ mu, const float* __restrict__ sigma,
    const _Float16* __restrict__ w1h, const _Float16* __restrict__ w1l,
    const float* __restrict__ w2, const int* __restrict__ batch,
    float* __restrict__ sumE, float* __restrict__ sumEH)
{
    // xs_h/xs_l: [64 nodes][264 f16]  (row stride 528B -> 2-way bank alias, free)
    // post-GEMM overlay: Hs [64][132] f32 = 33792B sits exactly on xs_h;
    // spart/esc/bseg live in the freed xs_l half (also 33792B).
    __shared__ unsigned char smem[64 * 264 * 2 * 2];   // 67584 B
    _Float16* xs_h = (_Float16*)smem;
    _Float16* xs_l = xs_h + 64 * 264;
    float*    Hs   = (float*)smem;                     // [64][132] f32 overlay
    float*    tail = (float*)(smem + 64 * 264 * 2);    // xs_l region, free post-GEMM
    float*    spart = tail;                            // [64][4] att partials
    float*    esc   = tail + 256;                      // [64] exp(score)
    int*      bseg  = (int*)(tail + 320);              // [64] graph ids

    const int tid   = threadIdx.x;
    const int nBase = blockIdx.x * TSN;

    // ---- stage x tile as fp16 hi/lo ----
    {
        const float4* xg = (const float4*)x;   // 64 float4 per row
        #pragma unroll
        for (int r = 0; r < 8; ++r) {
            int idx  = r * 512 + tid;
            int row  = idx >> 6;       // 0..63
            int quad = idx & 63;       // f-quad
            float4 v = xg[(size_t)(nBase + row) * 64 + quad];
            half4 h, l;
            h[0] = (_Float16)v.x; l[0] = (_Float16)(v.x - (float)h[0]);
            h[1] = (_Float16)v.y; l[1] = (_Float16)(v.y - (float)h[1]);
            h[2] = (_Float16)v.z; l[2] = (_Float16)(v.z - (float)h[2]);
            h[3] = (_Float16)v.w; l[3] = (_Float16)(v.w - (float)h[3]);
            *(half4*)&xs_h[row * 264 + quad * 4] = h;
            *(half4*)&xs_l[row * 264 + quad * 4] = l;
        }
    }
    __syncthreads();

    const int wave  = tid >> 6;
    const int lane  = tid & 63;
    const int c15   = lane & 15;
    const int q     = lane >> 4;
    const int nhalf = wave >> 2;   // 0..1
    const int colq  = wave & 3;    // 0..3

    float h[2][2][4];              // [rt][ct][reg] persistent H accumulator
    #pragma unroll
    for (int rt = 0; rt < 2; ++rt)
        #pragma unroll
        for (int ct = 0; ct < 2; ++ct)
            #pragma unroll
            for (int rg = 0; rg < 4; ++rg) h[rt][ct][rg] = 0.f;

    #pragma unroll 1
    for (int k = 0; k < KMIX; ++k) {
        // prefetch mu/sigma for this k (consumed in epilogue, loads hide under MFMAs)
        float muv[2], cexp[2];
        #pragma unroll
        for (int ct = 0; ct < 2; ++ct) {
            int col = k * 128 + colq * 32 + ct * 16 + c15;
            muv[ct] = mu[col];
            float sg = sigma[col];
            // exp(-0.5*d*d*iv) == exp2(d*d * cexp),  cexp = -0.5*log2e*iv
            cexp[ct] = (-0.5f * LOG2E) / (1e-15f + sg * sg);
        }

        // hoisted per-k B fragment base pointers (fc stride = 512 halfs)
        const _Float16* pBh0 = gh + ((size_t)((k * 8 + colq * 2 + 0) * 8) * 64 + lane) * 8;
        const _Float16* pBh1 = gh + ((size_t)((k * 8 + colq * 2 + 1) * 8) * 64 + lane) * 8;
        const _Float16* pBl0 = gl + ((size_t)((k * 8 + colq * 2 + 0) * 8) * 64 + lane) * 8;
        const _Float16* pBl1 = gl + ((size_t)((k * 8 + colq * 2 + 1) * 8) * 64 + lane) * 8;

        floatx4 acc[2][2];
        #pragma unroll
        for (int rt = 0; rt < 2; ++rt)
            #pragma unroll
            for (int ct = 0; ct < 2; ++ct) acc[rt][ct] = (floatx4)0.f;

        // ping-pong B registers; prime fc=0
        half8 Bh[2][2], Bl[2][2];   // [buf][ct]
        Bh[0][0] = *(const half8*)(pBh0);
        Bh[0][1] = *(const half8*)(pBh1);
        Bl[0][0] = *(const half8*)(pBl0);
        Bl[0][1] = *(const half8*)(pBl1);

        #pragma unroll
        for (int fc = 0; fc < 8; ++fc) {
            const int cur = fc & 1;
            const int nxt = cur ^ 1;
            if (fc < 7) {   // prefetch next fc's B frags (hide L2 latency under MFMAs)
                Bh[nxt][0] = *(const half8*)(pBh0 + (fc + 1) * 512);
                Bh[nxt][1] = *(const half8*)(pBh1 + (fc + 1) * 512);
                Bl[nxt][0] = *(const half8*)(pBl0 + (fc + 1) * 512);
                Bl[nxt][1] = *(const half8*)(pBl1 + (fc + 1) * 512);
            }
            const int f0 = fc * 32 + q * 8;
            half8 Ah[2], Al[2];
            #pragma unroll
            for (int rt = 0; rt < 2; ++rt) {
                int node = nhalf * 32 + rt * 16 + c15;
                Ah[rt] = *(const half8*)&xs_h[node * 264 + f0];
                Al[rt] = *(const half8*)&xs_l[node * 264 + f0];
            }
            #pragma unroll
            for (int rt = 0; rt < 2; ++rt)
                #pragma unroll
                for (int ct = 0; ct < 2; ++ct) {
                    acc[rt][ct] = __builtin_amdgcn_mfma_f32_16x16x32_f16(Ah[rt], Bh[cur][ct], acc[rt][ct], 0, 0, 0);
                    acc[rt][ct] = __builtin_amdgcn_mfma_f32_16x16x32_f16(Ah[rt], Bl[cur][ct], acc[rt][ct], 0, 0, 0);
                    acc[rt][ct] = __builtin_amdgcn_mfma_f32_16x16x32_f16(Al[rt], Bh[cur][ct], acc[rt][ct], 0, 0, 0);
                }
        }

        // gaussian epilogue: C layout col = lane&15, row = q*4 + reg
        #pragma unroll
        for (int ct = 0; ct < 2; ++ct) {
            #pragma unroll
            for (int rt = 0; rt < 2; ++rt)
                #pragma unroll
                for (int rg = 0; rg < 4; ++rg) {
                    float o = acc[rt][ct][rg];
                    float d = o - muv[ct];
                    h[rt][ct][rg] = fmaf(o, EXP2(d * d * cexp[ct]), h[rt][ct][rg]);
                }
        }
    }

    // ---- H -> LDS overlay (xs_h region); bseg into freed xs_l region ----
    __syncthreads();                   // all xs reads done before overlays
    const int HS_LD = MDIM + 4;
    #pragma unroll
    for (int rt = 0; rt < 2; ++rt)
        #pragma unroll
        for (int ct = 0; ct < 2; ++ct)
            #pragma unroll
            for (int rg = 0; rg < 4; ++rg) {
                int n = nhalf * 32 + rt * 16 + q * 4 + rg;
                int m = colq * 32 + ct * 16 + c15;
                Hs[n * HS_LD + m] = h[rt][ct][rg];
            }
    if (tid < 64) bseg[tid] = batch[nBase + tid];
    __syncthreads();

    // ---- attention via MFMA: dots = H @ w1^T (fp16 split), same wave tiling
    {
        floatx4 datt[2][2];
        #pragma unroll
        for (int rt = 0; rt < 2; ++rt)
            #pragma unroll
            for (int ct = 0; ct < 2; ++ct) datt[rt][ct] = (floatx4)0.f;

        #pragma unroll
        for (int mc = 0; mc < 4; ++mc) {
            half8 Ahh[2], All[2];
            #pragma unroll
            for (int rt = 0; rt < 2; ++rt) {
                int node = nhalf * 32 + rt * 16 + c15;
                const float* hp = &Hs[node * HS_LD + mc * 32 + q * 8];
                #pragma unroll
                for (int j = 0; j < 8; ++j) {
                    float v = hp[j];
                    _Float16 hi = (_Float16)v;
                    Ahh[rt][j] = hi;
                    All[rt][j] = (_Float16)(v - (float)hi);
                }
            }
            #pragma unroll
            for (int ct = 0; ct < 2; ++ct) {
                int frag = (colq * 2 + ct) * 4 + mc;
                size_t off = ((size_t)frag * 64 + lane) * 8;
                half8 Bhh = *(const half8*)(w1h + off);
                half8 Bll = *(const half8*)(w1l + off);
                #pragma unroll
                for (int rt = 0; rt < 2; ++rt) {
                    datt[rt][ct] = __builtin_amdgcn_mfma_f32_16x16x32_f16(Ahh[rt], Bhh, datt[rt][ct], 0, 0, 0);
                    datt[rt][ct] = __builtin_amdgcn_mfma_f32_16x16x32_f16(Ahh[rt], Bll, datt[rt][ct], 0, 0, 0);
                    datt[rt][ct] = __builtin_amdgcn_mfma_f32_16x16x32_f16(All[rt], Bhh, datt[rt][ct], 0, 0, 0);
                }
            }
        }

        // tanh * w2, reduce over wave's 32 atts -> spart[node][colq]
        float w2v[2];
        #pragma unroll
        for (int ct = 0; ct < 2; ++ct) w2v[ct] = w2[colq * 32 + ct * 16 + c15];

        #pragma unroll
        for (int rt = 0; rt < 2; ++rt) {
            #pragma unroll
            for (int rg = 0; rg < 4; ++rg) {
                float p = 0.f;
                #pragma unroll
                for (int ct = 0; ct < 2; ++ct) {
                    float dot = datt[rt][ct][rg];
                    float e2 = EXP2(2.f * LOG2E * dot);    // = exp(2*dot)
                    float av = 1.f - 2.f / (e2 + 1.f);     // tanh(dot)
                    p = fmaf(av, w2v[ct], p);
                }
                p += __shfl_xor(p, 1);
                p += __shfl_xor(p, 2);
                p += __shfl_xor(p, 4);
                p += __shfl_xor(p, 8);
                if (c15 == 0) {
                    int n = nhalf * 32 + rt * 16 + q * 4 + rg;
                    spart[n * 4 + colq] = p;
                }
            }
        }
    }
    __syncthreads();
    // ---- scores -> e = exp(score) (no max shift needed: |score| <= ~12) ----
    if (tid < 64) {
        const float* sp = &spart[tid * 4];
        float s = (sp[0] + sp[1]) + (sp[2] + sp[3]);
        esc[tid] = EXP2(LOG2E * s);
    }
    __syncthreads();

    // ---- in-block segmented pooling: atomicAdd e*H and e per graph ----
    {
        const int col = tid & 127;     // m column
        const int grp = tid >> 7;      // 0..3, 16 nodes each
        const int n0  = grp * 16;
        float partial = 0.f;
        int cur = bseg[n0];
        #pragma unroll 1
        for (int i = 0; i < 16; ++i) {
            int n = n0 + i;
            int b = bseg[n];
            if (b != cur) {
                atomicAdd(&sumEH[(size_t)cur * MDIM + col], partial);
                partial = 0.f; cur = b;
            }
            partial = fmaf(esc[n], Hs[n * HS_LD + col], partial);
        }
        atomicAdd(&sumEH[(size_t)cur * MDIM + col], partial);

        if (tid < 64) {   // segment leaders accumulate sumE (<=3 atomics/block)
            bool lead = (tid == 0) || (bseg[tid] != bseg[tid - 1]);
            if (lead) {
                int b = bseg[tid];
                float s = 0.f;
                for (int j = tid; j < 64 && bseg[j] == b; ++j) s += esc[j];
                atomicAdd(&sumE[b], s);
            }
        }
    }
}

// ---------------------------------------------------------------------------
// Kernel 2: out[g][m] = sumEH[g][m] / sumE[g]   (1024*128 elems)
// ---------------------------------------------------------------------------
__global__ __launch_bounds__(256) void normalize_out(
    const float* __restrict__ acc, float* __restrict__ out)
{
    int i = blockIdx.x * 256 + threadIdx.x;   // 0..131071
    const float* sumE  = acc;
    const float* sumEH = acc + NGRAPH;
    float e = sumE[i >> 7];
    out[i] = sumEH[i] / (e + 1e-30f);         // empty graph -> 0, matches ref
}

// ---------------------------------------------------------------------------
extern "C" void kernel_launch(void* const* d_in, const int* in_sizes, int n_in,
                              void* d_out, int out_size, void* d_ws, size_t ws_size,
                              hipStream_t stream)
{
    const float* x     = (const float*)d_in[0];
    const float* g     = (const float*)d_in[1];
    const float* mu    = (const float*)d_in[2];
    const float* sigma = (const float*)d_in[3];
    const float* w1    = (const float*)d_in[4];
    const float* w2    = (const float*)d_in[5];
    const int*   batch = (const int*)d_in[6];
    float* out = (float*)d_out;

    // ws: acc [1024*(1+128)] f32 | gh | gl | w1h | w1l   (~1.6 MB total)
    float*    accp = (float*)d_ws;
    _Float16* ghp  = (_Float16*)(accp + NGRAPH * (MDIM + 1));
    _Float16* glp  = ghp + (size_t)FDIM * KMIX * MDIM;
    _Float16* w1hp = glp + (size_t)FDIM * KMIX * MDIM;
    _Float16* w1lp = w1hp + (size_t)ATTD * MDIM;

    pack_zero<<<652, 256, 0, stream>>>(g, w1, ghp, glp, w1hp, w1lp, accp);
    fused_forward<<<N_NODES / TSN, 512, 0, stream>>>(x, ghp, glp, mu, sigma,
                                                     w1hp, w1lp, w2, batch,
                                                     accp, accp + NGRAPH);
    normalize_out<<<NGRAPH * MDIM / 256, 256, 0, stream>>>(accp, out);
}

// Round 3
// 620.618 us; speedup vs baseline: 1.8684x; 1.8684x over previous
//
#include <hip/hip_runtime.h>
#include <hip/hip_bf16.h>
#include <hip/hip_fp16.h>
#include <math.h>

// Problem constants (fixed by reference)
#define N_NODES 200000
#define FDIM    256     // F
#define MDIM    128     // M
#define KMIX    8       // K mixtures
#define ATTD    128     // ATT
#define NGRAPH  1024
#define TSN     64      // nodes per block

#define EXP2(x) __builtin_amdgcn_exp2f(x)
#define LOG2E   1.44269504f

typedef _Float16 half8 __attribute__((ext_vector_type(8)));
typedef _Float16 half4 __attribute__((ext_vector_type(4)));
typedef float    floatx4 __attribute__((ext_vector_type(4)));

// ---------------------------------------------------------------------------
// Kernel 0: split g AND w1 (fp32) into fp16 hi/lo, packed in MFMA B-frag order,
// plus zero the per-graph accumulators (sumE[1024] ++ sumEH[1024][128]).
// Blocks 0..127: g.   frag idx = (k*8 + ctg)*8 + fc ; 64 lanes x half8.
// Blocks 128..135: w1. frag idx = ctg*4 + mc.
// Blocks 136..651: zero acc (516*256 = 132096 = 1024*129 exactly).
// B layout (16x16x32 f16): col = lane&15, kdim = (lane>>4)*8 + j.
// ---------------------------------------------------------------------------
__global__ __launch_bounds__(256) void pack_zero(
    const float* __restrict__ g, const float* __restrict__ w1,
    _Float16* __restrict__ gh, _Float16* __restrict__ gl,
    _Float16* __restrict__ w1h, _Float16* __restrict__ w1l,
    float* __restrict__ acc)
{
    if (blockIdx.x < 128) {
        int t    = blockIdx.x * 256 + threadIdx.x;   // 0..32767
        int lane = t & 63;
        int frag = t >> 6;         // 0..511
        int fc   = frag & 7;
        int ctg  = (frag >> 3) & 7;
        int k    = frag >> 6;
        int col  = k * 128 + ctg * 16 + (lane & 15);
        int f0   = fc * 32 + (lane >> 4) * 8;
        half8 vh, vl;
        #pragma unroll
        for (int j = 0; j < 8; ++j) {
            float v = g[(size_t)(f0 + j) * 1024 + col];
            _Float16 h = (_Float16)v;
            vh[j] = h;
            vl[j] = (_Float16)(v - (float)h);
        }
        *(half8*)(gh + (size_t)t * 8) = vh;
        *(half8*)(gl + (size_t)t * 8) = vl;
    } else if (blockIdx.x < 136) {
        int t    = (blockIdx.x - 128) * 256 + threadIdx.x;   // 0..2047
        int lane = t & 63;
        int frag = t >> 6;         // 0..31
        int mc   = frag & 3;
        int ctg  = frag >> 2;
        int att  = ctg * 16 + (lane & 15);
        int m0   = mc * 32 + (lane >> 4) * 8;
        half8 vh, vl;
        #pragma unroll
        for (int j = 0; j < 8; ++j) {
            float v = w1[att * MDIM + m0 + j];
            _Float16 h = (_Float16)v;
            vh[j] = h;
            vl[j] = (_Float16)(v - (float)h);
        }
        *(half8*)(w1h + (size_t)t * 8) = vh;
        *(half8*)(w1l + (size_t)t * 8) = vl;
    } else {
        int i = (blockIdx.x - 136) * 256 + threadIdx.x;
        if (i < NGRAPH * (MDIM + 1)) acc[i] = 0.f;
    }
}

// ---------------------------------------------------------------------------
// Kernel 1: fused x@g (fp16-split MFMA) -> gaussian -> H -> attention (MFMA)
//   -> in-block softmax-numerator pooling via f32 atomics.
//   grid: N/64 blocks x 512 threads (8 waves).
//   wave w: n-half = w>>2 (32 nodes, rt=2), col-quarter = w&3 (32 cols, ct=2).
//   R3: revert R2's ping-pong (compiler kept fc runtime -> rule-#20 scratch
//   spill, 513MB of scratch stores). Instead: k-PAIRING (KK=2) on the R1
//   structure — one A-fragment load feeds both k's (A is k-invariant), so
//   A LDS traffic + bank conflicts halve, barriers drop 8->4, and each fc
//   body runs 24 MFMAs (vs 12) per stall point. All register arrays are
//   indexed ONLY by fully-unrolled compile-time kk/rt/ct; fc stays a plain
//   runtime loop with no fc-indexed arrays.
// ---------------------------------------------------------------------------
__global__ __launch_bounds__(512, 4) void fused_forward(
    const float* __restrict__ x,
    const _Float16* __restrict__ gh, const _Float16* __restrict__ gl,
    const float* __restrict__ mu, const float* __restrict__ sigma,
    const _Float16* __restrict__ w1h, const _Float16* __restrict__ w1l,
    const float* __restrict__ w2, const int* __restrict__ batch,
    float* __restrict__ sumE, float* __restrict__ sumEH)
{
    // xs_h/xs_l: [64 nodes][264 f16]  (row stride 528B -> 2-way bank alias, free)
    // post-GEMM overlay: Hs [64][132] f32 = 33792B sits exactly on xs_h;
    // spart/esc/bseg live in the freed xs_l half (also 33792B).
    __shared__ unsigned char smem[64 * 264 * 2 * 2];   // 67584 B
    _Float16* xs_h = (_Float16*)smem;
    _Float16* xs_l = xs_h + 64 * 264;
    float*    Hs   = (float*)smem;                     // [64][132] f32 overlay
    float*    tail = (float*)(smem + 64 * 264 * 2);    // xs_l region, free post-GEMM
    float*    spart = tail;                            // [64][4] att partials
    float*    esc   = tail + 256;                      // [64] exp(score)
    int*      bseg  = (int*)(tail + 320);              // [64] graph ids

    const int tid   = threadIdx.x;
    const int nBase = blockIdx.x * TSN;

    // ---- stage x tile as fp16 hi/lo ----
    {
        const float4* xg = (const float4*)x;   // 64 float4 per row
        #pragma unroll
        for (int r = 0; r < 8; ++r) {
            int idx  = r * 512 + tid;
            int row  = idx >> 6;       // 0..63
            int quad = idx & 63;       // f-quad
            float4 v = xg[(size_t)(nBase + row) * 64 + quad];
            half4 h, l;
            h[0] = (_Float16)v.x; l[0] = (_Float16)(v.x - (float)h[0]);
            h[1] = (_Float16)v.y; l[1] = (_Float16)(v.y - (float)h[1]);
            h[2] = (_Float16)v.z; l[2] = (_Float16)(v.z - (float)h[2]);
            h[3] = (_Float16)v.w; l[3] = (_Float16)(v.w - (float)h[3]);
            *(half4*)&xs_h[row * 264 + quad * 4] = h;
            *(half4*)&xs_l[row * 264 + quad * 4] = l;
        }
    }
    __syncthreads();

    const int wave  = tid >> 6;
    const int lane  = tid & 63;
    const int c15   = lane & 15;
    const int q     = lane >> 4;
    const int nhalf = wave >> 2;   // 0..1
    const int colq  = wave & 3;    // 0..3

    float h[2][2][4];              // [rt][ct][reg] persistent H accumulator
    #pragma unroll
    for (int rt = 0; rt < 2; ++rt)
        #pragma unroll
        for (int ct = 0; ct < 2; ++ct)
            #pragma unroll
            for (int rg = 0; rg < 4; ++rg) h[rt][ct][rg] = 0.f;

    #pragma unroll 1
    for (int k2 = 0; k2 < KMIX; k2 += 2) {
        __syncthreads();   // 4 cohort barriers (was 8): wave pairs share B frags in L1

        // prefetch mu/sigma for both k's (consumed in epilogue, hide under MFMAs)
        float muv[2][2], cgau[2][2];
        #pragma unroll
        for (int kk = 0; kk < 2; ++kk)
            #pragma unroll
            for (int ct = 0; ct < 2; ++ct) {
                int col = (k2 + kk) * 128 + colq * 32 + ct * 16 + c15;
                muv[kk][ct] = mu[col];
                float sg = sigma[col];
                // exp(-0.5*d*d*iv) == exp2(d*d * cgau),  cgau = -0.5*log2e*iv
                cgau[kk][ct] = (-0.5f * LOG2E) / (1e-15f + sg * sg);
            }

        floatx4 acc[2][2][2];   // [kk][rt][ct]
        #pragma unroll
        for (int kk = 0; kk < 2; ++kk)
            #pragma unroll
            for (int rt = 0; rt < 2; ++rt)
                #pragma unroll
                for (int ct = 0; ct < 2; ++ct) acc[kk][rt][ct] = (floatx4)0.f;

        #pragma unroll 1
        for (int fc = 0; fc < 8; ++fc) {
            const int f0 = fc * 32 + q * 8;
            half8 Ah[2], Al[2];
            #pragma unroll
            for (int rt = 0; rt < 2; ++rt) {
                int node = nhalf * 32 + rt * 16 + c15;
                Ah[rt] = *(const half8*)&xs_h[node * 264 + f0];
                Al[rt] = *(const half8*)&xs_l[node * 264 + f0];
            }
            half8 Bh[2][2], Bl[2][2];   // [kk][ct], all indices compile-time
            #pragma unroll
            for (int kk = 0; kk < 2; ++kk)
                #pragma unroll
                for (int ct = 0; ct < 2; ++ct) {
                    size_t off = ((size_t)(((k2 + kk) * 8 + colq * 2 + ct) * 8 + fc) * 64 + lane) * 8;
                    Bh[kk][ct] = *(const half8*)(gh + off);
                    Bl[kk][ct] = *(const half8*)(gl + off);
                }
            #pragma unroll
            for (int kk = 0; kk < 2; ++kk)
                #pragma unroll
                for (int rt = 0; rt < 2; ++rt)
                    #pragma unroll
                    for (int ct = 0; ct < 2; ++ct) {
                        acc[kk][rt][ct] = __builtin_amdgcn_mfma_f32_16x16x32_f16(Ah[rt], Bh[kk][ct], acc[kk][rt][ct], 0, 0, 0);
                        acc[kk][rt][ct] = __builtin_amdgcn_mfma_f32_16x16x32_f16(Ah[rt], Bl[kk][ct], acc[kk][rt][ct], 0, 0, 0);
                        acc[kk][rt][ct] = __builtin_amdgcn_mfma_f32_16x16x32_f16(Al[rt], Bh[kk][ct], acc[kk][rt][ct], 0, 0, 0);
                    }
        }

        // gaussian epilogue: C layout col = lane&15, row = q*4 + reg
        #pragma unroll
        for (int kk = 0; kk < 2; ++kk)
            #pragma unroll
            for (int ct = 0; ct < 2; ++ct)
                #pragma unroll
                for (int rt = 0; rt < 2; ++rt)
                    #pragma unroll
                    for (int rg = 0; rg < 4; ++rg) {
                        float o = acc[kk][rt][ct][rg];
                        float d = o - muv[kk][ct];
                        h[rt][ct][rg] = fmaf(o, EXP2(d * d * cgau[kk][ct]), h[rt][ct][rg]);
                    }
    }

    // ---- H -> LDS overlay (xs_h region); bseg into freed xs_l region ----
    __syncthreads();                   // all xs reads done before overlays
    const int HS_LD = MDIM + 4;
    #pragma unroll
    for (int rt = 0; rt < 2; ++rt)
        #pragma unroll
        for (int ct = 0; ct < 2; ++ct)
            #pragma unroll
            for (int rg = 0; rg < 4; ++rg) {
                int n = nhalf * 32 + rt * 16 + q * 4 + rg;
                int m = colq * 32 + ct * 16 + c15;
                Hs[n * HS_LD + m] = h[rt][ct][rg];
            }
    if (tid < 64) bseg[tid] = batch[nBase + tid];
    __syncthreads();

    // ---- attention via MFMA: dots = H @ w1^T (fp16 split), same wave tiling
    {
        floatx4 datt[2][2];
        #pragma unroll
        for (int rt = 0; rt < 2; ++rt)
            #pragma unroll
            for (int ct = 0; ct < 2; ++ct) datt[rt][ct] = (floatx4)0.f;

        #pragma unroll
        for (int mc = 0; mc < 4; ++mc) {
            half8 Ahh[2], All[2];
            #pragma unroll
            for (int rt = 0; rt < 2; ++rt) {
                int node = nhalf * 32 + rt * 16 + c15;
                const float* hp = &Hs[node * HS_LD + mc * 32 + q * 8];
                #pragma unroll
                for (int j = 0; j < 8; ++j) {
                    float v = hp[j];
                    _Float16 hi = (_Float16)v;
                    Ahh[rt][j] = hi;
                    All[rt][j] = (_Float16)(v - (float)hi);
                }
            }
            #pragma unroll
            for (int ct = 0; ct < 2; ++ct) {
                int frag = (colq * 2 + ct) * 4 + mc;
                size_t off = ((size_t)frag * 64 + lane) * 8;
                half8 Bhh = *(const half8*)(w1h + off);
                half8 Bll = *(const half8*)(w1l + off);
                #pragma unroll
                for (int rt = 0; rt < 2; ++rt) {
                    datt[rt][ct] = __builtin_amdgcn_mfma_f32_16x16x32_f16(Ahh[rt], Bhh, datt[rt][ct], 0, 0, 0);
                    datt[rt][ct] = __builtin_amdgcn_mfma_f32_16x16x32_f16(Ahh[rt], Bll, datt[rt][ct], 0, 0, 0);
                    datt[rt][ct] = __builtin_amdgcn_mfma_f32_16x16x32_f16(All[rt], Bhh, datt[rt][ct], 0, 0, 0);
                }
            }
        }

        // tanh * w2, reduce over wave's 32 atts -> spart[node][colq]
        float w2v[2];
        #pragma unroll
        for (int ct = 0; ct < 2; ++ct) w2v[ct] = w2[colq * 32 + ct * 16 + c15];

        #pragma unroll
        for (int rt = 0; rt < 2; ++rt) {
            #pragma unroll
            for (int rg = 0; rg < 4; ++rg) {
                float p = 0.f;
                #pragma unroll
                for (int ct = 0; ct < 2; ++ct) {
                    float dot = datt[rt][ct][rg];
                    float e2 = EXP2(2.f * LOG2E * dot);    // = exp(2*dot)
                    float av = 1.f - 2.f / (e2 + 1.f);     // tanh(dot)
                    p = fmaf(av, w2v[ct], p);
                }
                p += __shfl_xor(p, 1);
                p += __shfl_xor(p, 2);
                p += __shfl_xor(p, 4);
                p += __shfl_xor(p, 8);
                if (c15 == 0) {
                    int n = nhalf * 32 + rt * 16 + q * 4 + rg;
                    spart[n * 4 + colq] = p;
                }
            }
        }
    }
    __syncthreads();
    // ---- scores -> e = exp(score) (no max shift needed: |score| <= ~12) ----
    if (tid < 64) {
        const float* sp = &spart[tid * 4];
        float s = (sp[0] + sp[1]) + (sp[2] + sp[3]);
        esc[tid] = EXP2(LOG2E * s);
    }
    __syncthreads();

    // ---- in-block segmented pooling: atomicAdd e*H and e per graph ----
    {
        const int col = tid & 127;     // m column
        const int grp = tid >> 7;      // 0..3, 16 nodes each
        const int n0  = grp * 16;
        float partial = 0.f;
        int cur = bseg[n0];
        #pragma unroll 1
        for (int i = 0; i < 16; ++i) {
            int n = n0 + i;
            int b = bseg[n];
            if (b != cur) {
                atomicAdd(&sumEH[(size_t)cur * MDIM + col], partial);
                partial = 0.f; cur = b;
            }
            partial = fmaf(esc[n], Hs[n * HS_LD + col], partial);
        }
        atomicAdd(&sumEH[(size_t)cur * MDIM + col], partial);

        if (tid < 64) {   // segment leaders accumulate sumE (<=3 atomics/block)
            bool lead = (tid == 0) || (bseg[tid] != bseg[tid - 1]);
            if (lead) {
                int b = bseg[tid];
                float s = 0.f;
                for (int j = tid; j < 64 && bseg[j] == b; ++j) s += esc[j];
                atomicAdd(&sumE[b], s);
            }
        }
    }
}

// ---------------------------------------------------------------------------
// Kernel 2: out[g][m] = sumEH[g][m] / sumE[g]   (1024*128 elems)
// ---------------------------------------------------------------------------
__global__ __launch_bounds__(256) void normalize_out(
    const float* __restrict__ acc, float* __restrict__ out)
{
    int i = blockIdx.x * 256 + threadIdx.x;   // 0..131071
    const float* sumE  = acc;
    const float* sumEH = acc + NGRAPH;
    float e = sumE[i >> 7];
    out[i] = sumEH[i] / (e + 1e-30f);         // empty graph -> 0, matches ref
}

// ---------------------------------------------------------------------------
extern "C" void kernel_launch(void* const* d_in, const int* in_sizes, int n_in,
                              void* d_out, int out_size, void* d_ws, size_t ws_size,
                              hipStream_t stream)
{
    const float* x     = (const float*)d_in[0];
    const float* g     = (const float*)d_in[1];
    const float* mu    = (const float*)d_in[2];
    const float* sigma = (const float*)d_in[3];
    const float* w1    = (const float*)d_in[4];
    const float* w2    = (const float*)d_in[5];
    const int*   batch = (const int*)d_in[6];
    float* out = (float*)d_out;

    // ws: acc [1024*(1+128)] f32 | gh | gl | w1h | w1l   (~1.6 MB total)
    float*    accp = (float*)d_ws;
    _Float16* ghp  = (_Float16*)(accp + NGRAPH * (MDIM + 1));
    _Float16* glp  = ghp + (size_t)FDIM * KMIX * MDIM;
    _Float16* w1hp = glp + (size_t)FDIM * KMIX * MDIM;
    _Float16* w1lp = w1hp + (size_t)ATTD * MDIM;

    pack_zero<<<652, 256, 0, stream>>>(g, w1, ghp, glp, w1hp, w1lp, accp);
    fused_forward<<<N_NODES / TSN, 512, 0, stream>>>(x, ghp, glp, mu, sigma,
                                                     w1hp, w1lp, w2, batch,
                                                     accp, accp + NGRAPH);
    normalize_out<<<NGRAPH * MDIM / 256, 256, 0, stream>>>(accp, out);
}